// Round 14
// baseline (360.842 us; speedup 1.0000x reference)
//
#include <hip/hip_runtime.h>
#include <cstdint>
#include <cstddef>

typedef _Float16 f16;
typedef __attribute__((ext_vector_type(8))) _Float16 f16x8;  // MFMA A/B frag
typedef __attribute__((ext_vector_type(2))) _Float16 f16x2;
typedef __attribute__((ext_vector_type(4))) float f32x4;     // MFMA acc

#if defined(__has_builtin)
#if __has_builtin(__builtin_amdgcn_fdot2)
#define HAS_FDOT2 1
#endif
#endif

// ---- f16 bit helpers -------------------------------------------------------
__device__ __forceinline__ float hu2f(unsigned int u16) {
    f16 h; unsigned short s = (unsigned short)u16;
    __builtin_memcpy(&h, &s, 2); return (float)h;
}
__device__ __forceinline__ unsigned short f2hu(float f) {
    f16 h = (f16)f;
    unsigned short u; __builtin_memcpy(&u, &h, 2); return u;
}
__device__ __forceinline__ void unpk8(const uint4 u, float* f) {
    f[0] = hu2f(u.x & 0xffffu); f[1] = hu2f(u.x >> 16);
    f[2] = hu2f(u.y & 0xffffu); f[3] = hu2f(u.y >> 16);
    f[4] = hu2f(u.z & 0xffffu); f[5] = hu2f(u.z >> 16);
    f[6] = hu2f(u.w & 0xffffu); f[7] = hu2f(u.w >> 16);
}
__device__ __forceinline__ unsigned int packh2(float a, float b) {
    return (unsigned int)f2hu(a) | ((unsigned int)f2hu(b) << 16);
}
__device__ __forceinline__ float dotacc(unsigned int gh, unsigned int q, float acc) {
#ifdef HAS_FDOT2
    f16x2 a, b;
    __builtin_memcpy(&a, &gh, 4);
    __builtin_memcpy(&b, &q, 4);
    return __builtin_amdgcn_fdot2(a, b, acc, false);
#else
    return fmaf(hu2f(gh & 0xffffu), hu2f(q & 0xffffu),
                fmaf(hu2f(gh >> 16), hu2f(q >> 16), acc));
#endif
}

// ---------------------------------------------------------------------------
// Weight prep: OIHW f32 -> MFMA A-fragment f16 (blocks 0..8 convs, 9 = convT).
// ---------------------------------------------------------------------------
struct WSrc { const float* w[10]; };

__global__ __launch_bounds__(256) void prep_k(WSrc src, f16* __restrict__ wp,
                                              f16* __restrict__ wpT) {
    const int l = blockIdx.x;
    if (l == 9) {
        const float* wt = src.w[9];
        for (int e = threadIdx.x; e < 4096; e += 256) {
            const int j = e & 7;
            const int lane = (e >> 3) & 63;
            const int mt = e >> 9;
            const int m = mt * 16 + (lane & 15);
            const int k = ((lane >> 4) << 3) + j;     // ci
            wpT[e] = (f16)wt[k * 128 + m];            // m = co*4 + a*2 + b
        }
        return;
    }
    const int CI[9]  = {16, 16, 16, 32, 32, 32, 32, 16, 16};
    const int CO[9]  = {16, 16, 32, 32, 32, 32, 16, 16, 16};
    const int OFF[9] = {0, 3072, 6144, 12288, 21504, 30720, 39936, 44544, 47616};
    const int cin = CI[l], cout = CO[l], nct = cout / 16;
    const int nt = (cin == 32) ? 9 : 6;
    const int sz = nt * nct * 512;
    const float* w = src.w[l];
    f16* dst = wp + OFF[l];
    for (int e = threadIdx.x; e < sz; e += 256) {
        const int j = e & 7;
        const int lane = (e >> 3) & 63;
        const int r = e >> 9;
        const int ct = r % nct, tp = r / nct;
        const int co = ct * 16 + (lane & 15);
        const int kk = ((lane >> 4) << 3) + j;
        float v;
        if (cin == 32) {
            const int ci = kk, ky = tp / 3, kx = tp % 3;
            v = w[((co * 32 + ci) * 3 + ky) * 3 + kx];
        } else {
            const int ci = kk & 15, dxs = kk >> 4;
            const int ky = tp >> 1, kx = (tp & 1) * 2 + dxs;
            v = (kx < 3) ? w[((co * 16 + ci) * 3 + ky) * 3 + kx] : 0.0f;
        }
        dst[e] = (f16)v;
    }
}

// ---------------------------------------------------------------------------
// x (NCHW f32, 16ch) -> NHWC f16
// ---------------------------------------------------------------------------
__global__ __launch_bounds__(256) void xtonhwc_k(
    const float* __restrict__ x, f16* __restrict__ xh)
{
    const int idx = blockIdx.x * 256 + threadIdx.x;   // 4*262144
    const int n = idx >> 18, px = idx & 262143;
    const float* xp = x + (size_t)n * 16 * 262144 + px;
    unsigned short r[16];
    #pragma unroll
    for (int c = 0; c < 16; ++c) r[c] = f2hu(xp[(size_t)c * 262144]);
    __builtin_memcpy(xh + (size_t)idx * 16, r, 32);
}

// ---------------------------------------------------------------------------
// Implicit-GEMM 3x3 conv, ROWS-row wave blocking (ROWS=2 or 4).
// Tap rows y0-1..y0+ROWS loaded once; tap row r feeds output rows
// o in [max(0,r-2), min(ROWS-1,r)] with ky=r-o. MFMA count unchanged vs
// 1-row; loads/output-row: CIN16 24->16(R2)->12(R4); CIN32 36->24->18.
// POOL:  also emit 2x2 maxpool (requires even row pairs; RNE monotone).
// SPREP: also emit S(p) from f16-rounded accumulators + exact-f32 x part.
// ---------------------------------------------------------------------------
template<int CIN, int COUT, bool RELU, int LW, int ROWS, bool POOL, bool SPREP>
__global__ __launch_bounds__(256) void convm2_k(
    const f16* __restrict__ in, const f16* __restrict__ wp,
    const float* __restrict__ bias, f16* __restrict__ out,
    f16* __restrict__ pout, const float* __restrict__ xin,
    const float* __restrict__ fp, float* __restrict__ Sbuf)
{
    constexpr int Wd = 1 << LW;
    constexpr int PLANE = Wd * Wd;
    constexpr int NCT = COUT / 16;
    constexpr int NT = (CIN == 32) ? 9 : 6;
    constexpr int CB = CIN * 2;
    constexpr int COLB = Wd / 256;               // col blocks per row group

    const int lane = threadIdx.x & 63;
    const int l4 = lane >> 4;
    const int lm = lane & 15;
    const int wv = threadIdx.x >> 6;
    const int n = blockIdx.y;
    const int y0 = (blockIdx.x / COLB) * ROWS;
    const int xw = (blockIdx.x % COLB) * 256 + wv * 64;

    f16x8 afr[NT][NCT];
    #pragma unroll
    for (int tp = 0; tp < NT; ++tp)
        #pragma unroll
        for (int ct = 0; ct < NCT; ++ct)
            __builtin_memcpy(&afr[tp][ct],
                wp + ((size_t)(tp * NCT + ct) * 64 + lane) * 8, 16);

    f32x4 acc[ROWS][4][NCT];
    #pragma unroll
    for (int ct = 0; ct < NCT; ++ct) {
        const float4 bv = *reinterpret_cast<const float4*>(bias + ct * 16 + l4 * 4);
        #pragma unroll
        for (int o = 0; o < ROWS; ++o)
            #pragma unroll
            for (int t = 0; t < 4; ++t) {
                acc[o][t][ct][0] = bv.x; acc[o][t][ct][1] = bv.y;
                acc[o][t][ct][2] = bv.z; acc[o][t][ct][3] = bv.w;
            }
    }

    bool okL[4], okR[4];
    #pragma unroll
    for (int t = 0; t < 4; ++t) {
        const int xl = xw + t * 16 + lm;
        okL[t] = (xl != 0)      || (CIN == 16 && lane >= 32);
        okR[t] = (xl != Wd - 1) || (CIN == 16 && lane >= 32);
    }

    int laneoff;
    if (CIN == 32) laneoff = lm * 64 + l4 * 16;
    else           laneoff = lm * 32 + (l4 >> 1) * 32 + (l4 & 1) * 16;

    const char* base = (const char*)in
        + ((size_t)n * PLANE + (size_t)y0 * Wd + xw) * CB + laneoff;

    #pragma unroll
    for (int r = 0; r < ROWS + 2; ++r) {           // tap row y0-1+r
        const int ry = y0 - 1 + r;
        if ((unsigned)ry >= (unsigned)Wd) continue;   // uniform per block
        const char* rb = base + (r - 1) * Wd * CB;
        if (CIN == 32) {
            #pragma unroll
            for (int dx = 0; dx < 3; ++dx)
                #pragma unroll
                for (int t = 0; t < 4; ++t) {
                    uint4 u = *reinterpret_cast<const uint4*>(rb + ((dx - 1) + t * 16) * 64);
                    if (dx == 0 && !okL[t]) { u.x = 0; u.y = 0; u.z = 0; u.w = 0; }
                    if (dx == 2 && !okR[t]) { u.x = 0; u.y = 0; u.z = 0; u.w = 0; }
                    f16x8 b; __builtin_memcpy(&b, &u, 16);
                    #pragma unroll
                    for (int o = 0; o < ROWS; ++o) {
                        if (o > r || o < r - 2) continue;     // compile-time
                        const int ky = r - o;
                        #pragma unroll
                        for (int ct = 0; ct < NCT; ++ct)
                            acc[o][t][ct] = __builtin_amdgcn_mfma_f32_16x16x32_f16(
                                afr[ky * 3 + dx][ct], b, acc[o][t][ct], 0, 0, 0);
                    }
                }
        } else {
            #pragma unroll
            for (int p = 0; p < 2; ++p)
                #pragma unroll
                for (int t = 0; t < 4; ++t) {
                    uint4 u = *reinterpret_cast<const uint4*>(rb + (p ? 32 : -32) + t * 512);
                    if (p == 0 && !okL[t]) { u.x = 0; u.y = 0; u.z = 0; u.w = 0; }
                    if (p == 1 && !okR[t]) { u.x = 0; u.y = 0; u.z = 0; u.w = 0; }
                    f16x8 b; __builtin_memcpy(&b, &u, 16);
                    #pragma unroll
                    for (int o = 0; o < ROWS; ++o) {
                        if (o > r || o < r - 2) continue;     // compile-time
                        const int ky = r - o;
                        #pragma unroll
                        for (int ct = 0; ct < NCT; ++ct)
                            acc[o][t][ct] = __builtin_amdgcn_mfma_f32_16x16x32_f16(
                                afr[ky * 2 + p][ct], b, acc[o][t][ct], 0, 0, 0);
                    }
                }
        }
    }

    #pragma unroll
    for (int o = 0; o < ROWS; ++o) {
        char* ob = (char*)out
            + ((size_t)n * PLANE + (size_t)(y0 + o) * Wd + xw) * (COUT * 2);
        #pragma unroll
        for (int t = 0; t < 4; ++t)
            #pragma unroll
            for (int ct = 0; ct < NCT; ++ct) {
                float a0 = acc[o][t][ct][0], a1 = acc[o][t][ct][1];
                float a2 = acc[o][t][ct][2], a3 = acc[o][t][ct][3];
                if (RELU) {
                    a0 = fmaxf(a0, 0.f); a1 = fmaxf(a1, 0.f);
                    a2 = fmaxf(a2, 0.f); a3 = fmaxf(a3, 0.f);
                }
                ushort4 pk;
                pk.x = f2hu(a0); pk.y = f2hu(a1); pk.z = f2hu(a2); pk.w = f2hu(a3);
                *reinterpret_cast<ushort4*>(
                    ob + ((size_t)(t * 16 + lm) * COUT + ct * 16 + l4 * 4) * 2) = pk;
            }
    }

    if constexpr (POOL) {
        // fused 2x2 maxpool over row pairs (2o, 2o+1) -> pooled row (y0>>1)+o
        constexpr int HPL = (Wd >> 1) * (Wd >> 1);
        #pragma unroll
        for (int o = 0; o < ROWS / 2; ++o) {
            #pragma unroll
            for (int t = 0; t < 4; ++t) {
                const int col = xw + t * 16 + lm;
                #pragma unroll
                for (int ct = 0; ct < NCT; ++ct) {
                    float m[4];
                    #pragma unroll
                    for (int rg = 0; rg < 4; ++rg) {
                        m[rg] = fmaxf(acc[2 * o][t][ct][rg], acc[2 * o + 1][t][ct][rg]);
                        m[rg] = fmaxf(m[rg], __shfl_xor(m[rg], 1));
                    }
                    if ((lm & 1) == 0) {
                        ushort4 pk;
                        pk.x = f2hu(m[0]); pk.y = f2hu(m[1]);
                        pk.z = f2hu(m[2]); pk.w = f2hu(m[3]);
                        char* pb = (char*)pout
                            + (((size_t)n * HPL
                                + (size_t)((y0 >> 1) + o) * (Wd >> 1) + (col >> 1))
                               * COUT + ct * 16 + l4 * 4) * 2;
                        *reinterpret_cast<ushort4*>(pb) = pk;
                    }
                }
            }
        }
    }

    if constexpr (SPREP) {
        // fused S(p): feats part from f16-rounded acc (== stored feats),
        // cross-lane reduce over l4 groups, plus exact-f32 x part. NCT==1.
        float fpv[4];
        #pragma unroll
        for (int rg = 0; rg < 4; ++rg) fpv[rg] = fp[11 + l4 * 4 + rg];
        #pragma unroll
        for (int o = 0; o < ROWS; ++o) {
            #pragma unroll
            for (int t = 0; t < 4; ++t) {
                float s = 0.f;
                #pragma unroll
                for (int rg = 0; rg < 4; ++rg) {
                    const float v = (float)(f16)acc[o][t][0][rg];
                    s = fmaf(fpv[rg] * v, v, s);
                }
                s += __shfl_xor(s, 16);
                s += __shfl_xor(s, 32);
                if (l4 == 0) {
                    const int px = (y0 + o) * Wd + xw + t * 16 + lm;
                    const float* xp = xin + (size_t)n * 16 * PLANE + px;
                    #pragma unroll
                    for (int i = 0; i < 11; ++i) {
                        const float v = xp[(size_t)i * PLANE];
                        s = fmaf(fp[i] * v, v, s);
                    }
                    Sbuf[(size_t)n * PLANE + px] = s;
                }
            }
        }
    }
}

// ---------------------------------------------------------------------------
// ConvT 2x2 s2 + skip add via MFMA (unchanged, f16).
// ---------------------------------------------------------------------------
__global__ __launch_bounds__(256) void convTm_k(
    const f16* __restrict__ e, const f16* __restrict__ wpT,
    const float* __restrict__ bt, f16* __restrict__ du)
{
    __shared__ float lds[4][16 * 132];
    const int lane = threadIdx.x & 63;
    const int wv = threadIdx.x >> 6;
    const int l4 = lane >> 4, lm = lane & 15;
    const int n = blockIdx.y;
    const int row = blockIdx.x;
    const int j0 = wv * 64;

    f16x8 afr[8];
    #pragma unroll
    for (int mt = 0; mt < 8; ++mt)
        __builtin_memcpy(&afr[mt], wpT + ((size_t)(mt * 64 + lane)) * 8, 16);

    float bco[8];
    #pragma unroll
    for (int mt = 0; mt < 8; ++mt) bco[mt] = bt[mt * 4 + l4];

    const char* ep = (const char*)e + ((size_t)n * 65536 + (size_t)row * 256 + j0) * 64;
    float* L = lds[wv];

    const int ra = lane >> 5;
    const int ru = lane & 31;
    const int rj = ru >> 1;
    const int rb = ru & 1;

    #pragma unroll 1
    for (int nt = 0; nt < 4; ++nt) {
        f16x8 bf;
        __builtin_memcpy(&bf, ep + (nt * 16 + lm) * 64 + l4 * 16, 16);

        #pragma unroll
        for (int mt = 0; mt < 8; ++mt) {
            f32x4 acc;
            acc[0] = bco[mt]; acc[1] = bco[mt]; acc[2] = bco[mt]; acc[3] = bco[mt];
            acc = __builtin_amdgcn_mfma_f32_16x16x32_f16(afr[mt], bf, acc, 0, 0, 0);
            float4 st; st.x = acc[0]; st.y = acc[1]; st.z = acc[2]; st.w = acc[3];
            *reinterpret_cast<float4*>(L + lm * 132 + mt * 16 + l4 * 4) = st;
        }
        __syncthreads();

        {
            const float* Ls = L + rj * 132 + ra * 2 + rb;
            char* dp = (char*)du
                + (((size_t)n * 262144
                    + (size_t)(2 * row + ra) * 512
                    + (size_t)(2 * (j0 + nt * 16 + rj) + rb)) * 32) * 2;
            float add[32];
            #pragma unroll
            for (int co = 0; co < 32; ++co) add[co] = Ls[co * 4];
            #pragma unroll
            for (int q = 0; q < 4; ++q) {
                uint4 u = *reinterpret_cast<const uint4*>(dp + q * 16);
                float dv[8]; unpk8(u, dv);
                unsigned short r[8];
                #pragma unroll
                for (int k = 0; k < 8; ++k) r[k] = f2hu(dv[k] + add[q * 8 + k]);
                __builtin_memcpy(dp + q * 16, r, 16);
            }
        }
        __syncthreads();
    }
}

// ---------------------------------------------------------------------------
// Bilateral, factored, y-PAIR, serial chains + f16 dot2 feats path (R12).
// ---------------------------------------------------------------------------
__global__ __launch_bounds__(256) void bil_k(
    const float* __restrict__ xin, const f16* __restrict__ feats,
    const float* __restrict__ Sbuf, const float* __restrict__ fp,
    float* __restrict__ out)
{
    constexpr int PLANE = 512 * 512;
    const int n = blockIdx.y;
    const int rp = blockIdx.x >> 1;                       // row-pair 0..255
    const int xx = ((blockIdx.x & 1) << 8) + threadIdx.x; // 0..511
    const int y0 = ((rp >> 1) << 2) + (rp & 1);           // rows y0, y0+2

    const float sy = fp[27], sx = fp[28];

    const int p0 = y0 * 512 + xx;
    const float* xb = xin + (size_t)n * 16 * PLANE + p0;
    const char* fb = (const char*)feats + ((size_t)n * PLANE + p0) * 32;
    const float* Sb = Sbuf + (size_t)n * PLANE + p0;

    float g0[11], g1[11];
    #pragma unroll
    for (int i = 0; i < 11; ++i) {
        g0[i] = fp[i] * xb[(size_t)i * PLANE];
        g1[i] = fp[i] * xb[(size_t)i * PLANE + 1024];
    }
    unsigned int g0h[8], g1h[8];
    {
        uint4 cu0 = *reinterpret_cast<const uint4*>(fb);
        uint4 cu1 = *reinterpret_cast<const uint4*>(fb + 16);
        const unsigned int* cq = (const unsigned int*)&cu0;
        const unsigned int* cq2 = (const unsigned int*)&cu1;
        #pragma unroll
        for (int j = 0; j < 8; ++j) {
            const unsigned int q = (j < 4) ? cq[j] : cq2[j - 4];
            g0h[j] = packh2(fp[11 + 2 * j] * hu2f(q & 0xffffu),
                            fp[12 + 2 * j] * hu2f(q >> 16));
        }
        cu0 = *reinterpret_cast<const uint4*>(fb + 32768);
        cu1 = *reinterpret_cast<const uint4*>(fb + 32768 + 16);
        #pragma unroll
        for (int j = 0; j < 8; ++j) {
            const unsigned int q = (j < 4) ? ((const unsigned int*)&cu0)[j]
                                           : ((const unsigned int*)&cu1)[j - 4];
            g1h[j] = packh2(fp[11 + 2 * j] * hu2f(q & 0xffffu),
                            fp[12 + 2 * j] * hu2f(q >> 16));
        }
    }
    const float Sp0 = Sb[0];
    const float Sp1 = Sb[1024];

    float num0[11], num1[11];
    #pragma unroll
    for (int i = 0; i < 11; ++i) { num0[i] = 0.f; num1[i] = 0.f; }
    float den0 = 0.f, den1 = 0.f;

    #pragma unroll
    for (int o = -4; o <= 6; o += 2) {
        const int r = y0 + o;
        if ((unsigned)r > 511u) continue;                 // uniform per block
        const float b0 = fmaf(sy, (float)(o * o), Sp0);
        const float b1 = fmaf(sy, (float)((o - 2) * (o - 2)), Sp1);
        const float* xr = xb + o * 512;
        const char* fr = fb + (ptrdiff_t)o * 512 * 32;
        const float* Sr = Sb + o * 512;
        #pragma unroll
        for (int dx = -2; dx <= 2; ++dx) {
            const int xv = xx + 2 * dx;
            if ((unsigned)xv > 511u) continue;            // edge lanes only
            const int off = dx * 2;

            float sv[11];
            #pragma unroll
            for (int i = 0; i < 11; ++i) sv[i] = xr[(size_t)i * PLANE + off];
            const uint4 u0 = *reinterpret_cast<const uint4*>(fr + off * 32);
            const uint4 u1 = *reinterpret_cast<const uint4*>(fr + off * 32 + 16);
            const unsigned int* fq = (const unsigned int*)&u0;
            const unsigned int* fq2 = (const unsigned int*)&u1;
            const float Sq = Sr[off] + sx * (float)(4 * dx * dx);

            if (o <= 4) {                                 // p0 tap
                float cr = g0[0] * sv[0];
                #pragma unroll
                for (int i = 1; i < 11; ++i) cr = fmaf(g0[i], sv[i], cr);
                #pragma unroll
                for (int j = 0; j < 8; ++j)
                    cr = dotacc(g0h[j], (j < 4) ? fq[j] : fq2[j - 4], cr);
                const float w = __expf(fmaf(-2.0f, cr, Sq + b0));
                #pragma unroll
                for (int i = 0; i < 11; ++i) num0[i] = fmaf(w, sv[i], num0[i]);
                den0 += w;
            }
            if (o >= -2) {                                // p1 tap
                float cr = g1[0] * sv[0];
                #pragma unroll
                for (int i = 1; i < 11; ++i) cr = fmaf(g1[i], sv[i], cr);
                #pragma unroll
                for (int j = 0; j < 8; ++j)
                    cr = dotacc(g1h[j], (j < 4) ? fq[j] : fq2[j - 4], cr);
                const float w = __expf(fmaf(-2.0f, cr, Sq + b1));
                #pragma unroll
                for (int i = 0; i < 11; ++i) num1[i] = fmaf(w, sv[i], num1[i]);
                den1 += w;
            }
        }
    }

    const float i0 = 1.f / den0, i1 = 1.f / den1;
    float* ob = out + (size_t)n * 11 * PLANE + p0;
    #pragma unroll
    for (int i = 0; i < 11; ++i) {
        ob[(size_t)i * PLANE] = num0[i] * i0;
        ob[(size_t)i * PLANE + 1024] = num1[i] * i1;
    }
}

// ---------------------------------------------------------------------------
extern "C" void kernel_launch(void* const* d_in, const int* in_sizes, int n_in,
                              void* d_out, int out_size, void* d_ws, size_t ws_size,
                              hipStream_t stream)
{
    const float* x = (const float*)d_in[0];
    const float* Wv[9];
    const float* Bv[9];
    if (in_sizes[2] == 16) {
        for (int i = 0; i < 9; ++i) {
            Wv[i] = (const float*)d_in[1 + 2 * i];
            Bv[i] = (const float*)d_in[2 + 2 * i];
        }
    } else {
        for (int i = 0; i < 9; ++i) {
            Wv[i] = (const float*)d_in[1 + i];
            Bv[i] = (const float*)d_in[10 + i];
        }
    }
    const float* wt = (const float*)d_in[19];
    const float* bt = (const float*)d_in[20];
    const float* fp = (const float*)d_in[21];
    float* out = (float*)d_out;

    constexpr size_t MiB = 1ull << 20;
    char* ws = (char*)d_ws;

    f16* wp  = (f16*)(ws + 4096);
    f16* wpT = (f16*)(ws + 256 * 1024);
    f16 *xh, *du, *bufA, *bufB;
    if (ws_size >= 165 * MiB) {
        xh   = (f16*)(ws + 1 * MiB);
        du   = (f16*)(ws + 34 * MiB);
        bufA = (f16*)(ws + 99 * MiB);
        bufB = (f16*)(ws + 132 * MiB);
    } else if (ws_size >= 132 * MiB) {
        xh   = (f16*)(ws + 1 * MiB);
        du   = (f16*)(ws + 34 * MiB);
        bufA = (f16*)(ws + 99 * MiB);
        bufB = xh;
    } else {
        xh   = (f16*)((char*)d_out + 256);
        du   = (f16*)(ws + 1 * MiB);
        bufA = (f16*)(ws + 66 * MiB);
        bufB = xh;
    }
    float* Sbuf = (float*)du;   // du dead after conv6; reused for S (4 MiB)

    WSrc srcs;
    for (int i = 0; i < 9; ++i) srcs.w[i] = Wv[i];
    srcs.w[9] = wt;

    prep_k<<<10, 256, 0, stream>>>(srcs, wp, wpT);
    xtonhwc_k<<<4096, 256, 0, stream>>>(x, xh);

    const dim3 blk(256);
    const dim3 g512r4(256, 4);  // 512^2, 4-row: 128 row-quads x 2 col halves
    const dim3 g512r2(512, 4);  // 512^2, 2-row
    const dim3 g256r2(128, 4);  // 256^2, 2-row
    const dim3 gT(256, 4);

    convm2_k<16, 16, true,  9, 4, false, false><<<g512r4, blk, 0, stream>>>(
        xh,   wp + 0,     Bv[0], bufA, nullptr, nullptr, nullptr, nullptr);
    convm2_k<16, 16, true,  9, 4, false, false><<<g512r4, blk, 0, stream>>>(
        bufA, wp + 3072,  Bv[1], bufB, nullptr, nullptr, nullptr, nullptr);
    // conv2 + fused 2x2 maxpool (pooled e -> bufA); COUT32 -> stay 2-row
    convm2_k<16, 32, false, 9, 2, true,  false><<<g512r2, blk, 0, stream>>>(
        bufB, wp + 6144,  Bv[2], du,   bufA,    nullptr, nullptr, nullptr);

    convm2_k<32, 32, true,  8, 2, false, false><<<g256r2, blk, 0, stream>>>(
        bufA, wp + 12288, Bv[3], bufB, nullptr, nullptr, nullptr, nullptr);
    convm2_k<32, 32, true,  8, 2, false, false><<<g256r2, blk, 0, stream>>>(
        bufB, wp + 21504, Bv[4], bufA, nullptr, nullptr, nullptr, nullptr);
    convm2_k<32, 32, true,  8, 2, false, false><<<g256r2, blk, 0, stream>>>(
        bufA, wp + 30720, Bv[5], bufB, nullptr, nullptr, nullptr, nullptr);

    convTm_k<<<gT, blk, 0, stream>>>(bufB, wpT, bt, du);

    convm2_k<32, 16, true,  9, 4, false, false><<<g512r4, blk, 0, stream>>>(
        du,   wp + 39936, Bv[6], bufA, nullptr, nullptr, nullptr, nullptr);
    convm2_k<16, 16, true,  9, 4, false, false><<<g512r4, blk, 0, stream>>>(
        bufA, wp + 44544, Bv[7], bufB, nullptr, nullptr, nullptr, nullptr);
    // conv8 + fused S precompute (feats -> bufA, S -> Sbuf in dead du region)
    convm2_k<16, 16, false, 9, 4, false, true ><<<g512r4, blk, 0, stream>>>(
        bufB, wp + 47616, Bv[8], bufA, nullptr, x, fp, Sbuf);

    bil_k<<<dim3(512, 4), blk, 0, stream>>>(x, bufA, Sbuf, fp, out);

    (void)n_in; (void)out_size;
}

// Round 15
// 341.824 us; speedup vs baseline: 1.0556x; 1.0556x over previous
//
#include <hip/hip_runtime.h>
#include <cstdint>
#include <cstddef>

typedef _Float16 f16;
typedef __attribute__((ext_vector_type(8))) _Float16 f16x8;  // MFMA A/B frag
typedef __attribute__((ext_vector_type(2))) _Float16 f16x2;
typedef __attribute__((ext_vector_type(4))) float f32x4;     // MFMA acc

#if defined(__has_builtin)
#if __has_builtin(__builtin_amdgcn_fdot2)
#define HAS_FDOT2 1
#endif
#endif

// ---- f16 bit helpers -------------------------------------------------------
__device__ __forceinline__ float hu2f(unsigned int u16) {
    f16 h; unsigned short s = (unsigned short)u16;
    __builtin_memcpy(&h, &s, 2); return (float)h;
}
__device__ __forceinline__ unsigned short f2hu(float f) {
    f16 h = (f16)f;
    unsigned short u; __builtin_memcpy(&u, &h, 2); return u;
}
__device__ __forceinline__ void unpk8(const uint4 u, float* f) {
    f[0] = hu2f(u.x & 0xffffu); f[1] = hu2f(u.x >> 16);
    f[2] = hu2f(u.y & 0xffffu); f[3] = hu2f(u.y >> 16);
    f[4] = hu2f(u.z & 0xffffu); f[5] = hu2f(u.z >> 16);
    f[6] = hu2f(u.w & 0xffffu); f[7] = hu2f(u.w >> 16);
}
__device__ __forceinline__ unsigned int packh2(float a, float b) {
    return (unsigned int)f2hu(a) | ((unsigned int)f2hu(b) << 16);
}
__device__ __forceinline__ float dotacc(unsigned int gh, unsigned int q, float acc) {
#ifdef HAS_FDOT2
    f16x2 a, b;
    __builtin_memcpy(&a, &gh, 4);
    __builtin_memcpy(&b, &q, 4);
    return __builtin_amdgcn_fdot2(a, b, acc, false);
#else
    return fmaf(hu2f(gh & 0xffffu), hu2f(q & 0xffffu),
                fmaf(hu2f(gh >> 16), hu2f(q >> 16), acc));
#endif
}

// ---------------------------------------------------------------------------
// Weight prep: OIHW f32 -> MFMA A-fragment f16 (blocks 0..8 convs, 9 = convT).
// ---------------------------------------------------------------------------
struct WSrc { const float* w[10]; };

__global__ __launch_bounds__(256) void prep_k(WSrc src, f16* __restrict__ wp,
                                              f16* __restrict__ wpT) {
    const int l = blockIdx.x;
    if (l == 9) {
        const float* wt = src.w[9];
        for (int e = threadIdx.x; e < 4096; e += 256) {
            const int j = e & 7;
            const int lane = (e >> 3) & 63;
            const int mt = e >> 9;
            const int m = mt * 16 + (lane & 15);
            const int k = ((lane >> 4) << 3) + j;     // ci
            wpT[e] = (f16)wt[k * 128 + m];            // m = co*4 + a*2 + b
        }
        return;
    }
    const int CI[9]  = {16, 16, 16, 32, 32, 32, 32, 16, 16};
    const int CO[9]  = {16, 16, 32, 32, 32, 32, 16, 16, 16};
    const int OFF[9] = {0, 3072, 6144, 12288, 21504, 30720, 39936, 44544, 47616};
    const int cin = CI[l], cout = CO[l], nct = cout / 16;
    const int nt = (cin == 32) ? 9 : 6;
    const int sz = nt * nct * 512;
    const float* w = src.w[l];
    f16* dst = wp + OFF[l];
    for (int e = threadIdx.x; e < sz; e += 256) {
        const int j = e & 7;
        const int lane = (e >> 3) & 63;
        const int r = e >> 9;
        const int ct = r % nct, tp = r / nct;
        const int co = ct * 16 + (lane & 15);
        const int kk = ((lane >> 4) << 3) + j;
        float v;
        if (cin == 32) {
            const int ci = kk, ky = tp / 3, kx = tp % 3;
            v = w[((co * 32 + ci) * 3 + ky) * 3 + kx];
        } else {
            const int ci = kk & 15, dxs = kk >> 4;
            const int ky = tp >> 1, kx = (tp & 1) * 2 + dxs;
            v = (kx < 3) ? w[((co * 16 + ci) * 3 + ky) * 3 + kx] : 0.0f;
        }
        dst[e] = (f16)v;
    }
}

// ---------------------------------------------------------------------------
// x (NCHW f32, 16ch) -> NHWC f16
// ---------------------------------------------------------------------------
__global__ __launch_bounds__(256) void xtonhwc_k(
    const float* __restrict__ x, f16* __restrict__ xh)
{
    const int idx = blockIdx.x * 256 + threadIdx.x;   // 4*262144
    const int n = idx >> 18, px = idx & 262143;
    const float* xp = x + (size_t)n * 16 * 262144 + px;
    unsigned short r[16];
    #pragma unroll
    for (int c = 0; c < 16; ++c) r[c] = f2hu(xp[(size_t)c * 262144]);
    __builtin_memcpy(xh + (size_t)idx * 16, r, 32);
}

// ---------------------------------------------------------------------------
// Implicit-GEMM 3x3 conv, 2-ROW wave blocking, generic LW (9=512^2, 8=256^2).
// POOL:  also emit 2x2-maxpooled output (conv2 path; RNE monotone =>
//        round(max)==max(round), bit-identical to separate pool).
// SPREP: also emit S(p) = sum_i cw_i v_i(p)^2 (conv8 path; feats part from
//        f16-rounded accumulators == stored feats; x part exact f32).
// 2-row is the resource/ILP sweet spot: 4-row (R14) and finer splits (R11)
// both regressed via occupancy/issue loss.
// ---------------------------------------------------------------------------
template<int CIN, int COUT, bool RELU, int LW, bool POOL, bool SPREP>
__global__ __launch_bounds__(256) void convm2_k(
    const f16* __restrict__ in, const f16* __restrict__ wp,
    const float* __restrict__ bias, f16* __restrict__ out,
    f16* __restrict__ pout, const float* __restrict__ xin,
    const float* __restrict__ fp, float* __restrict__ Sbuf)
{
    constexpr int Wd = 1 << LW;
    constexpr int PLANE = Wd * Wd;
    constexpr int NCT = COUT / 16;
    constexpr int NT = (CIN == 32) ? 9 : 6;
    constexpr int CB = CIN * 2;
    constexpr int COLB = Wd / 256;               // col blocks per row pair

    const int lane = threadIdx.x & 63;
    const int l4 = lane >> 4;
    const int lm = lane & 15;
    const int wv = threadIdx.x >> 6;
    const int n = blockIdx.y;
    const int y0 = (blockIdx.x / COLB) * 2;
    const int xw = (blockIdx.x % COLB) * 256 + wv * 64;

    f16x8 afr[NT][NCT];
    #pragma unroll
    for (int tp = 0; tp < NT; ++tp)
        #pragma unroll
        for (int ct = 0; ct < NCT; ++ct)
            __builtin_memcpy(&afr[tp][ct],
                wp + ((size_t)(tp * NCT + ct) * 64 + lane) * 8, 16);

    f32x4 acc[2][4][NCT];
    #pragma unroll
    for (int ct = 0; ct < NCT; ++ct) {
        const float4 bv = *reinterpret_cast<const float4*>(bias + ct * 16 + l4 * 4);
        #pragma unroll
        for (int o = 0; o < 2; ++o)
            #pragma unroll
            for (int t = 0; t < 4; ++t) {
                acc[o][t][ct][0] = bv.x; acc[o][t][ct][1] = bv.y;
                acc[o][t][ct][2] = bv.z; acc[o][t][ct][3] = bv.w;
            }
    }

    bool okL[4], okR[4];
    #pragma unroll
    for (int t = 0; t < 4; ++t) {
        const int xl = xw + t * 16 + lm;
        okL[t] = (xl != 0)      || (CIN == 16 && lane >= 32);
        okR[t] = (xl != Wd - 1) || (CIN == 16 && lane >= 32);
    }

    int laneoff;
    if (CIN == 32) laneoff = lm * 64 + l4 * 16;
    else           laneoff = lm * 32 + (l4 >> 1) * 32 + (l4 & 1) * 16;

    const char* base = (const char*)in
        + ((size_t)n * PLANE + (size_t)y0 * Wd + xw) * CB + laneoff;

    #pragma unroll
    for (int r = 0; r < 4; ++r) {                  // tap row y0-1+r
        const int ry = y0 - 1 + r;
        if ((unsigned)ry >= (unsigned)Wd) continue;   // uniform per block
        const char* rb = base + (r - 1) * Wd * CB;
        if (CIN == 32) {
            #pragma unroll
            for (int dx = 0; dx < 3; ++dx)
                #pragma unroll
                for (int t = 0; t < 4; ++t) {
                    uint4 u = *reinterpret_cast<const uint4*>(rb + ((dx - 1) + t * 16) * 64);
                    if (dx == 0 && !okL[t]) { u.x = 0; u.y = 0; u.z = 0; u.w = 0; }
                    if (dx == 2 && !okR[t]) { u.x = 0; u.y = 0; u.z = 0; u.w = 0; }
                    f16x8 b; __builtin_memcpy(&b, &u, 16);
                    if (r <= 2)                       // out row y0, ky=r
                        #pragma unroll
                        for (int ct = 0; ct < NCT; ++ct)
                            acc[0][t][ct] = __builtin_amdgcn_mfma_f32_16x16x32_f16(
                                afr[r * 3 + dx][ct], b, acc[0][t][ct], 0, 0, 0);
                    if (r >= 1)                       // out row y0+1, ky=r-1
                        #pragma unroll
                        for (int ct = 0; ct < NCT; ++ct)
                            acc[1][t][ct] = __builtin_amdgcn_mfma_f32_16x16x32_f16(
                                afr[(r - 1) * 3 + dx][ct], b, acc[1][t][ct], 0, 0, 0);
                }
        } else {
            #pragma unroll
            for (int p = 0; p < 2; ++p)
                #pragma unroll
                for (int t = 0; t < 4; ++t) {
                    uint4 u = *reinterpret_cast<const uint4*>(rb + (p ? 32 : -32) + t * 512);
                    if (p == 0 && !okL[t]) { u.x = 0; u.y = 0; u.z = 0; u.w = 0; }
                    if (p == 1 && !okR[t]) { u.x = 0; u.y = 0; u.z = 0; u.w = 0; }
                    f16x8 b; __builtin_memcpy(&b, &u, 16);
                    if (r <= 2)
                        #pragma unroll
                        for (int ct = 0; ct < NCT; ++ct)
                            acc[0][t][ct] = __builtin_amdgcn_mfma_f32_16x16x32_f16(
                                afr[r * 2 + p][ct], b, acc[0][t][ct], 0, 0, 0);
                    if (r >= 1)
                        #pragma unroll
                        for (int ct = 0; ct < NCT; ++ct)
                            acc[1][t][ct] = __builtin_amdgcn_mfma_f32_16x16x32_f16(
                                afr[(r - 1) * 2 + p][ct], b, acc[1][t][ct], 0, 0, 0);
                }
        }
    }

    #pragma unroll
    for (int o = 0; o < 2; ++o) {
        char* ob = (char*)out
            + ((size_t)n * PLANE + (size_t)(y0 + o) * Wd + xw) * (COUT * 2);
        #pragma unroll
        for (int t = 0; t < 4; ++t)
            #pragma unroll
            for (int ct = 0; ct < NCT; ++ct) {
                float a0 = acc[o][t][ct][0], a1 = acc[o][t][ct][1];
                float a2 = acc[o][t][ct][2], a3 = acc[o][t][ct][3];
                if (RELU) {
                    a0 = fmaxf(a0, 0.f); a1 = fmaxf(a1, 0.f);
                    a2 = fmaxf(a2, 0.f); a3 = fmaxf(a3, 0.f);
                }
                ushort4 pk;
                pk.x = f2hu(a0); pk.y = f2hu(a1); pk.z = f2hu(a2); pk.w = f2hu(a3);
                *reinterpret_cast<ushort4*>(
                    ob + ((size_t)(t * 16 + lm) * COUT + ct * 16 + l4 * 4) * 2) = pk;
            }
    }

    if constexpr (POOL) {
        // fused 2x2 maxpool over the (y0, y0+1) row pair -> pooled row y0/2
        constexpr int HPL = (Wd >> 1) * (Wd >> 1);
        #pragma unroll
        for (int t = 0; t < 4; ++t) {
            const int col = xw + t * 16 + lm;
            #pragma unroll
            for (int ct = 0; ct < NCT; ++ct) {
                float m[4];
                #pragma unroll
                for (int rg = 0; rg < 4; ++rg) {
                    m[rg] = fmaxf(acc[0][t][ct][rg], acc[1][t][ct][rg]);
                    m[rg] = fmaxf(m[rg], __shfl_xor(m[rg], 1));
                }
                if ((lm & 1) == 0) {
                    ushort4 pk;
                    pk.x = f2hu(m[0]); pk.y = f2hu(m[1]);
                    pk.z = f2hu(m[2]); pk.w = f2hu(m[3]);
                    char* pb = (char*)pout
                        + (((size_t)n * HPL + (size_t)(y0 >> 1) * (Wd >> 1) + (col >> 1))
                           * COUT + ct * 16 + l4 * 4) * 2;
                    *reinterpret_cast<ushort4*>(pb) = pk;
                }
            }
        }
    }

    if constexpr (SPREP) {
        // fused S(p): feats part from f16-rounded acc (== stored feats),
        // cross-lane reduce over l4 groups, plus exact-f32 x part. NCT==1.
        float fpv[4];
        #pragma unroll
        for (int rg = 0; rg < 4; ++rg) fpv[rg] = fp[11 + l4 * 4 + rg];
        #pragma unroll
        for (int o = 0; o < 2; ++o) {
            #pragma unroll
            for (int t = 0; t < 4; ++t) {
                float s = 0.f;
                #pragma unroll
                for (int rg = 0; rg < 4; ++rg) {
                    const float v = (float)(f16)acc[o][t][0][rg];
                    s = fmaf(fpv[rg] * v, v, s);
                }
                s += __shfl_xor(s, 16);
                s += __shfl_xor(s, 32);
                if (l4 == 0) {
                    const int px = (y0 + o) * Wd + xw + t * 16 + lm;
                    const float* xp = xin + (size_t)n * 16 * PLANE + px;
                    #pragma unroll
                    for (int i = 0; i < 11; ++i) {
                        const float v = xp[(size_t)i * PLANE];
                        s = fmaf(fp[i] * v, v, s);
                    }
                    Sbuf[(size_t)n * PLANE + px] = s;
                }
            }
        }
    }
}

// ---------------------------------------------------------------------------
// ConvT 2x2 s2 + skip add via MFMA (unchanged, f16).
// ---------------------------------------------------------------------------
__global__ __launch_bounds__(256) void convTm_k(
    const f16* __restrict__ e, const f16* __restrict__ wpT,
    const float* __restrict__ bt, f16* __restrict__ du)
{
    __shared__ float lds[4][16 * 132];
    const int lane = threadIdx.x & 63;
    const int wv = threadIdx.x >> 6;
    const int l4 = lane >> 4, lm = lane & 15;
    const int n = blockIdx.y;
    const int row = blockIdx.x;
    const int j0 = wv * 64;

    f16x8 afr[8];
    #pragma unroll
    for (int mt = 0; mt < 8; ++mt)
        __builtin_memcpy(&afr[mt], wpT + ((size_t)(mt * 64 + lane)) * 8, 16);

    float bco[8];
    #pragma unroll
    for (int mt = 0; mt < 8; ++mt) bco[mt] = bt[mt * 4 + l4];

    const char* ep = (const char*)e + ((size_t)n * 65536 + (size_t)row * 256 + j0) * 64;
    float* L = lds[wv];

    const int ra = lane >> 5;
    const int ru = lane & 31;
    const int rj = ru >> 1;
    const int rb = ru & 1;

    #pragma unroll 1
    for (int nt = 0; nt < 4; ++nt) {
        f16x8 bf;
        __builtin_memcpy(&bf, ep + (nt * 16 + lm) * 64 + l4 * 16, 16);

        #pragma unroll
        for (int mt = 0; mt < 8; ++mt) {
            f32x4 acc;
            acc[0] = bco[mt]; acc[1] = bco[mt]; acc[2] = bco[mt]; acc[3] = bco[mt];
            acc = __builtin_amdgcn_mfma_f32_16x16x32_f16(afr[mt], bf, acc, 0, 0, 0);
            float4 st; st.x = acc[0]; st.y = acc[1]; st.z = acc[2]; st.w = acc[3];
            *reinterpret_cast<float4*>(L + lm * 132 + mt * 16 + l4 * 4) = st;
        }
        __syncthreads();

        {
            const float* Ls = L + rj * 132 + ra * 2 + rb;
            char* dp = (char*)du
                + (((size_t)n * 262144
                    + (size_t)(2 * row + ra) * 512
                    + (size_t)(2 * (j0 + nt * 16 + rj) + rb)) * 32) * 2;
            float add[32];
            #pragma unroll
            for (int co = 0; co < 32; ++co) add[co] = Ls[co * 4];
            #pragma unroll
            for (int q = 0; q < 4; ++q) {
                uint4 u = *reinterpret_cast<const uint4*>(dp + q * 16);
                float dv[8]; unpk8(u, dv);
                unsigned short r[8];
                #pragma unroll
                for (int k = 0; k < 8; ++k) r[k] = f2hu(dv[k] + add[q * 8 + k]);
                __builtin_memcpy(dp + q * 16, r, 16);
            }
        }
        __syncthreads();
    }
}

// ---------------------------------------------------------------------------
// Bilateral, factored, y-PAIR, serial chains + f16 dot2 feats path (R12).
// ---------------------------------------------------------------------------
__global__ __launch_bounds__(256) void bil_k(
    const float* __restrict__ xin, const f16* __restrict__ feats,
    const float* __restrict__ Sbuf, const float* __restrict__ fp,
    float* __restrict__ out)
{
    constexpr int PLANE = 512 * 512;
    const int n = blockIdx.y;
    const int rp = blockIdx.x >> 1;                       // row-pair 0..255
    const int xx = ((blockIdx.x & 1) << 8) + threadIdx.x; // 0..511
    const int y0 = ((rp >> 1) << 2) + (rp & 1);           // rows y0, y0+2

    const float sy = fp[27], sx = fp[28];

    const int p0 = y0 * 512 + xx;
    const float* xb = xin + (size_t)n * 16 * PLANE + p0;
    const char* fb = (const char*)feats + ((size_t)n * PLANE + p0) * 32;
    const float* Sb = Sbuf + (size_t)n * PLANE + p0;

    float g0[11], g1[11];
    #pragma unroll
    for (int i = 0; i < 11; ++i) {
        g0[i] = fp[i] * xb[(size_t)i * PLANE];
        g1[i] = fp[i] * xb[(size_t)i * PLANE + 1024];
    }
    unsigned int g0h[8], g1h[8];
    {
        uint4 cu0 = *reinterpret_cast<const uint4*>(fb);
        uint4 cu1 = *reinterpret_cast<const uint4*>(fb + 16);
        const unsigned int* cq = (const unsigned int*)&cu0;
        const unsigned int* cq2 = (const unsigned int*)&cu1;
        #pragma unroll
        for (int j = 0; j < 8; ++j) {
            const unsigned int q = (j < 4) ? cq[j] : cq2[j - 4];
            g0h[j] = packh2(fp[11 + 2 * j] * hu2f(q & 0xffffu),
                            fp[12 + 2 * j] * hu2f(q >> 16));
        }
        cu0 = *reinterpret_cast<const uint4*>(fb + 32768);
        cu1 = *reinterpret_cast<const uint4*>(fb + 32768 + 16);
        #pragma unroll
        for (int j = 0; j < 8; ++j) {
            const unsigned int q = (j < 4) ? ((const unsigned int*)&cu0)[j]
                                           : ((const unsigned int*)&cu1)[j - 4];
            g1h[j] = packh2(fp[11 + 2 * j] * hu2f(q & 0xffffu),
                            fp[12 + 2 * j] * hu2f(q >> 16));
        }
    }
    const float Sp0 = Sb[0];
    const float Sp1 = Sb[1024];

    float num0[11], num1[11];
    #pragma unroll
    for (int i = 0; i < 11; ++i) { num0[i] = 0.f; num1[i] = 0.f; }
    float den0 = 0.f, den1 = 0.f;

    #pragma unroll
    for (int o = -4; o <= 6; o += 2) {
        const int r = y0 + o;
        if ((unsigned)r > 511u) continue;                 // uniform per block
        const float b0 = fmaf(sy, (float)(o * o), Sp0);
        const float b1 = fmaf(sy, (float)((o - 2) * (o - 2)), Sp1);
        const float* xr = xb + o * 512;
        const char* fr = fb + (ptrdiff_t)o * 512 * 32;
        const float* Sr = Sb + o * 512;
        #pragma unroll
        for (int dx = -2; dx <= 2; ++dx) {
            const int xv = xx + 2 * dx;
            if ((unsigned)xv > 511u) continue;            // edge lanes only
            const int off = dx * 2;

            float sv[11];
            #pragma unroll
            for (int i = 0; i < 11; ++i) sv[i] = xr[(size_t)i * PLANE + off];
            const uint4 u0 = *reinterpret_cast<const uint4*>(fr + off * 32);
            const uint4 u1 = *reinterpret_cast<const uint4*>(fr + off * 32 + 16);
            const unsigned int* fq = (const unsigned int*)&u0;
            const unsigned int* fq2 = (const unsigned int*)&u1;
            const float Sq = Sr[off] + sx * (float)(4 * dx * dx);

            if (o <= 4) {                                 // p0 tap
                float cr = g0[0] * sv[0];
                #pragma unroll
                for (int i = 1; i < 11; ++i) cr = fmaf(g0[i], sv[i], cr);
                #pragma unroll
                for (int j = 0; j < 8; ++j)
                    cr = dotacc(g0h[j], (j < 4) ? fq[j] : fq2[j - 4], cr);
                const float w = __expf(fmaf(-2.0f, cr, Sq + b0));
                #pragma unroll
                for (int i = 0; i < 11; ++i) num0[i] = fmaf(w, sv[i], num0[i]);
                den0 += w;
            }
            if (o >= -2) {                                // p1 tap
                float cr = g1[0] * sv[0];
                #pragma unroll
                for (int i = 1; i < 11; ++i) cr = fmaf(g1[i], sv[i], cr);
                #pragma unroll
                for (int j = 0; j < 8; ++j)
                    cr = dotacc(g1h[j], (j < 4) ? fq[j] : fq2[j - 4], cr);
                const float w = __expf(fmaf(-2.0f, cr, Sq + b1));
                #pragma unroll
                for (int i = 0; i < 11; ++i) num1[i] = fmaf(w, sv[i], num1[i]);
                den1 += w;
            }
        }
    }

    const float i0 = 1.f / den0, i1 = 1.f / den1;
    float* ob = out + (size_t)n * 11 * PLANE + p0;
    #pragma unroll
    for (int i = 0; i < 11; ++i) {
        ob[(size_t)i * PLANE] = num0[i] * i0;
        ob[(size_t)i * PLANE + 1024] = num1[i] * i1;
    }
}

// ---------------------------------------------------------------------------
extern "C" void kernel_launch(void* const* d_in, const int* in_sizes, int n_in,
                              void* d_out, int out_size, void* d_ws, size_t ws_size,
                              hipStream_t stream)
{
    const float* x = (const float*)d_in[0];
    const float* Wv[9];
    const float* Bv[9];
    if (in_sizes[2] == 16) {
        for (int i = 0; i < 9; ++i) {
            Wv[i] = (const float*)d_in[1 + 2 * i];
            Bv[i] = (const float*)d_in[2 + 2 * i];
        }
    } else {
        for (int i = 0; i < 9; ++i) {
            Wv[i] = (const float*)d_in[1 + i];
            Bv[i] = (const float*)d_in[10 + i];
        }
    }
    const float* wt = (const float*)d_in[19];
    const float* bt = (const float*)d_in[20];
    const float* fp = (const float*)d_in[21];
    float* out = (float*)d_out;

    constexpr size_t MiB = 1ull << 20;
    char* ws = (char*)d_ws;

    f16* wp  = (f16*)(ws + 4096);
    f16* wpT = (f16*)(ws + 256 * 1024);
    f16 *xh, *du, *bufA, *bufB;
    if (ws_size >= 165 * MiB) {
        xh   = (f16*)(ws + 1 * MiB);
        du   = (f16*)(ws + 34 * MiB);
        bufA = (f16*)(ws + 99 * MiB);
        bufB = (f16*)(ws + 132 * MiB);
    } else if (ws_size >= 132 * MiB) {
        xh   = (f16*)(ws + 1 * MiB);
        du   = (f16*)(ws + 34 * MiB);
        bufA = (f16*)(ws + 99 * MiB);
        bufB = xh;
    } else {
        xh   = (f16*)((char*)d_out + 256);
        du   = (f16*)(ws + 1 * MiB);
        bufA = (f16*)(ws + 66 * MiB);
        bufB = xh;
    }
    float* Sbuf = (float*)du;   // du dead after conv6; reused for S (4 MiB)

    WSrc srcs;
    for (int i = 0; i < 9; ++i) srcs.w[i] = Wv[i];
    srcs.w[9] = wt;

    prep_k<<<10, 256, 0, stream>>>(srcs, wp, wpT);
    xtonhwc_k<<<4096, 256, 0, stream>>>(x, xh);

    const dim3 blk(256);
    const dim3 g512(512, 4);    // 512^2: 256 row-pairs x 2 col halves
    const dim3 g256(128, 4);    // 256^2: 128 row-pairs x 1
    const dim3 gT(256, 4);

    convm2_k<16, 16, true,  9, false, false><<<g512, blk, 0, stream>>>(
        xh,   wp + 0,     Bv[0], bufA, nullptr, nullptr, nullptr, nullptr);
    convm2_k<16, 16, true,  9, false, false><<<g512, blk, 0, stream>>>(
        bufA, wp + 3072,  Bv[1], bufB, nullptr, nullptr, nullptr, nullptr);
    // conv2 + fused 2x2 maxpool (pooled e -> bufA)
    convm2_k<16, 32, false, 9, true,  false><<<g512, blk, 0, stream>>>(
        bufB, wp + 6144,  Bv[2], du,   bufA,    nullptr, nullptr, nullptr);

    convm2_k<32, 32, true,  8, false, false><<<g256, blk, 0, stream>>>(
        bufA, wp + 12288, Bv[3], bufB, nullptr, nullptr, nullptr, nullptr);
    convm2_k<32, 32, true,  8, false, false><<<g256, blk, 0, stream>>>(
        bufB, wp + 21504, Bv[4], bufA, nullptr, nullptr, nullptr, nullptr);
    convm2_k<32, 32, true,  8, false, false><<<g256, blk, 0, stream>>>(
        bufA, wp + 30720, Bv[5], bufB, nullptr, nullptr, nullptr, nullptr);

    convTm_k<<<gT, blk, 0, stream>>>(bufB, wpT, bt, du);

    convm2_k<32, 16, true,  9, false, false><<<g512, blk, 0, stream>>>(
        du,   wp + 39936, Bv[6], bufA, nullptr, nullptr, nullptr, nullptr);
    convm2_k<16, 16, true,  9, false, false><<<g512, blk, 0, stream>>>(
        bufA, wp + 44544, Bv[7], bufB, nullptr, nullptr, nullptr, nullptr);
    // conv8 + fused S precompute (feats -> bufA, S -> Sbuf in dead du region)
    convm2_k<16, 16, false, 9, false, true ><<<g512, blk, 0, stream>>>(
        bufB, wp + 47616, Bv[8], bufA, nullptr, x, fp, Sbuf);

    bil_k<<<dim3(512, 4), blk, 0, stream>>>(x, bufA, Sbuf, fp, out);

    (void)n_in; (void)out_size;
}

// Round 16
// 320.958 us; speedup vs baseline: 1.1243x; 1.0650x over previous
//
#include <hip/hip_runtime.h>
#include <cstdint>
#include <cstddef>

typedef _Float16 f16;
typedef __attribute__((ext_vector_type(8))) _Float16 f16x8;  // MFMA A/B frag
typedef __attribute__((ext_vector_type(2))) _Float16 f16x2;
typedef __attribute__((ext_vector_type(4))) float f32x4;     // MFMA acc

#if defined(__has_builtin)
#if __has_builtin(__builtin_amdgcn_fdot2)
#define HAS_FDOT2 1
#endif
#endif

// ---- f16 bit helpers -------------------------------------------------------
__device__ __forceinline__ float hu2f(unsigned int u16) {
    f16 h; unsigned short s = (unsigned short)u16;
    __builtin_memcpy(&h, &s, 2); return (float)h;
}
__device__ __forceinline__ unsigned short f2hu(float f) {
    f16 h = (f16)f;
    unsigned short u; __builtin_memcpy(&u, &h, 2); return u;
}
__device__ __forceinline__ void unpk8(const uint4 u, float* f) {
    f[0] = hu2f(u.x & 0xffffu); f[1] = hu2f(u.x >> 16);
    f[2] = hu2f(u.y & 0xffffu); f[3] = hu2f(u.y >> 16);
    f[4] = hu2f(u.z & 0xffffu); f[5] = hu2f(u.z >> 16);
    f[6] = hu2f(u.w & 0xffffu); f[7] = hu2f(u.w >> 16);
}
__device__ __forceinline__ unsigned int packh2(float a, float b) {
    return (unsigned int)f2hu(a) | ((unsigned int)f2hu(b) << 16);
}
__device__ __forceinline__ float dotacc(unsigned int gh, unsigned int q, float acc) {
#ifdef HAS_FDOT2
    f16x2 a, b;
    __builtin_memcpy(&a, &gh, 4);
    __builtin_memcpy(&b, &q, 4);
    return __builtin_amdgcn_fdot2(a, b, acc, false);
#else
    return fmaf(hu2f(gh & 0xffffu), hu2f(q & 0xffffu),
                fmaf(hu2f(gh >> 16), hu2f(q >> 16), acc));
#endif
}

// XCD-aware chunked block swizzle (MI355X has 8 XCDs; consecutive hardware
// blockIdx round-robin across XCDs). Requires nwg % 8 == 0 (all our grids:
// 512/256/128; gridDim.y offsets preserve phase since nwg%8==0). Bijective.
__device__ __forceinline__ int xcdswz(int bx, int nwg) {
    return (bx & 7) * (nwg >> 3) + (bx >> 3);
}

// ---------------------------------------------------------------------------
// Weight prep: OIHW f32 -> MFMA A-fragment f16 (blocks 0..8 convs, 9 = convT).
// ---------------------------------------------------------------------------
struct WSrc { const float* w[10]; };

__global__ __launch_bounds__(256) void prep_k(WSrc src, f16* __restrict__ wp,
                                              f16* __restrict__ wpT) {
    const int l = blockIdx.x;
    if (l == 9) {
        const float* wt = src.w[9];
        for (int e = threadIdx.x; e < 4096; e += 256) {
            const int j = e & 7;
            const int lane = (e >> 3) & 63;
            const int mt = e >> 9;
            const int m = mt * 16 + (lane & 15);
            const int k = ((lane >> 4) << 3) + j;     // ci
            wpT[e] = (f16)wt[k * 128 + m];            // m = co*4 + a*2 + b
        }
        return;
    }
    const int CI[9]  = {16, 16, 16, 32, 32, 32, 32, 16, 16};
    const int CO[9]  = {16, 16, 32, 32, 32, 32, 16, 16, 16};
    const int OFF[9] = {0, 3072, 6144, 12288, 21504, 30720, 39936, 44544, 47616};
    const int cin = CI[l], cout = CO[l], nct = cout / 16;
    const int nt = (cin == 32) ? 9 : 6;
    const int sz = nt * nct * 512;
    const float* w = src.w[l];
    f16* dst = wp + OFF[l];
    for (int e = threadIdx.x; e < sz; e += 256) {
        const int j = e & 7;
        const int lane = (e >> 3) & 63;
        const int r = e >> 9;
        const int ct = r % nct, tp = r / nct;
        const int co = ct * 16 + (lane & 15);
        const int kk = ((lane >> 4) << 3) + j;
        float v;
        if (cin == 32) {
            const int ci = kk, ky = tp / 3, kx = tp % 3;
            v = w[((co * 32 + ci) * 3 + ky) * 3 + kx];
        } else {
            const int ci = kk & 15, dxs = kk >> 4;
            const int ky = tp >> 1, kx = (tp & 1) * 2 + dxs;
            v = (kx < 3) ? w[((co * 16 + ci) * 3 + ky) * 3 + kx] : 0.0f;
        }
        dst[e] = (f16)v;
    }
}

// ---------------------------------------------------------------------------
// x (NCHW f32, 16ch) -> NHWC f16
// ---------------------------------------------------------------------------
__global__ __launch_bounds__(256) void xtonhwc_k(
    const float* __restrict__ x, f16* __restrict__ xh)
{
    const int idx = blockIdx.x * 256 + threadIdx.x;   // 4*262144
    const int n = idx >> 18, px = idx & 262143;
    const float* xp = x + (size_t)n * 16 * 262144 + px;
    unsigned short r[16];
    #pragma unroll
    for (int c = 0; c < 16; ++c) r[c] = f2hu(xp[(size_t)c * 262144]);
    __builtin_memcpy(xh + (size_t)idx * 16, r, 32);
}

// ---------------------------------------------------------------------------
// Implicit-GEMM 3x3 conv, 2-ROW wave blocking, generic LW (9=512^2, 8=256^2).
// XCD-swizzled blockIdx.x for L2 row-band locality (neighbor row-pairs share
// 2 of 4 tap rows).
// POOL:  also emit 2x2-maxpooled output (conv2 path; RNE monotone).
// SPREP: also emit S(p) (conv8 path; feats part from f16-rounded acc).
// ---------------------------------------------------------------------------
template<int CIN, int COUT, bool RELU, int LW, bool POOL, bool SPREP>
__global__ __launch_bounds__(256) void convm2_k(
    const f16* __restrict__ in, const f16* __restrict__ wp,
    const float* __restrict__ bias, f16* __restrict__ out,
    f16* __restrict__ pout, const float* __restrict__ xin,
    const float* __restrict__ fp, float* __restrict__ Sbuf)
{
    constexpr int Wd = 1 << LW;
    constexpr int PLANE = Wd * Wd;
    constexpr int NCT = COUT / 16;
    constexpr int NT = (CIN == 32) ? 9 : 6;
    constexpr int CB = CIN * 2;
    constexpr int COLB = Wd / 256;               // col blocks per row pair

    const int lane = threadIdx.x & 63;
    const int l4 = lane >> 4;
    const int lm = lane & 15;
    const int wv = threadIdx.x >> 6;
    const int n = blockIdx.y;
    const int bx = xcdswz(blockIdx.x, (Wd / 2) * COLB);
    const int y0 = (bx / COLB) * 2;
    const int xw = (bx % COLB) * 256 + wv * 64;

    f16x8 afr[NT][NCT];
    #pragma unroll
    for (int tp = 0; tp < NT; ++tp)
        #pragma unroll
        for (int ct = 0; ct < NCT; ++ct)
            __builtin_memcpy(&afr[tp][ct],
                wp + ((size_t)(tp * NCT + ct) * 64 + lane) * 8, 16);

    f32x4 acc[2][4][NCT];
    #pragma unroll
    for (int ct = 0; ct < NCT; ++ct) {
        const float4 bv = *reinterpret_cast<const float4*>(bias + ct * 16 + l4 * 4);
        #pragma unroll
        for (int o = 0; o < 2; ++o)
            #pragma unroll
            for (int t = 0; t < 4; ++t) {
                acc[o][t][ct][0] = bv.x; acc[o][t][ct][1] = bv.y;
                acc[o][t][ct][2] = bv.z; acc[o][t][ct][3] = bv.w;
            }
    }

    bool okL[4], okR[4];
    #pragma unroll
    for (int t = 0; t < 4; ++t) {
        const int xl = xw + t * 16 + lm;
        okL[t] = (xl != 0)      || (CIN == 16 && lane >= 32);
        okR[t] = (xl != Wd - 1) || (CIN == 16 && lane >= 32);
    }

    int laneoff;
    if (CIN == 32) laneoff = lm * 64 + l4 * 16;
    else           laneoff = lm * 32 + (l4 >> 1) * 32 + (l4 & 1) * 16;

    const char* base = (const char*)in
        + ((size_t)n * PLANE + (size_t)y0 * Wd + xw) * CB + laneoff;

    #pragma unroll
    for (int r = 0; r < 4; ++r) {                  // tap row y0-1+r
        const int ry = y0 - 1 + r;
        if ((unsigned)ry >= (unsigned)Wd) continue;   // uniform per block
        const char* rb = base + (r - 1) * Wd * CB;
        if (CIN == 32) {
            #pragma unroll
            for (int dx = 0; dx < 3; ++dx)
                #pragma unroll
                for (int t = 0; t < 4; ++t) {
                    uint4 u = *reinterpret_cast<const uint4*>(rb + ((dx - 1) + t * 16) * 64);
                    if (dx == 0 && !okL[t]) { u.x = 0; u.y = 0; u.z = 0; u.w = 0; }
                    if (dx == 2 && !okR[t]) { u.x = 0; u.y = 0; u.z = 0; u.w = 0; }
                    f16x8 b; __builtin_memcpy(&b, &u, 16);
                    if (r <= 2)                       // out row y0, ky=r
                        #pragma unroll
                        for (int ct = 0; ct < NCT; ++ct)
                            acc[0][t][ct] = __builtin_amdgcn_mfma_f32_16x16x32_f16(
                                afr[r * 3 + dx][ct], b, acc[0][t][ct], 0, 0, 0);
                    if (r >= 1)                       // out row y0+1, ky=r-1
                        #pragma unroll
                        for (int ct = 0; ct < NCT; ++ct)
                            acc[1][t][ct] = __builtin_amdgcn_mfma_f32_16x16x32_f16(
                                afr[(r - 1) * 3 + dx][ct], b, acc[1][t][ct], 0, 0, 0);
                }
        } else {
            #pragma unroll
            for (int p = 0; p < 2; ++p)
                #pragma unroll
                for (int t = 0; t < 4; ++t) {
                    uint4 u = *reinterpret_cast<const uint4*>(rb + (p ? 32 : -32) + t * 512);
                    if (p == 0 && !okL[t]) { u.x = 0; u.y = 0; u.z = 0; u.w = 0; }
                    if (p == 1 && !okR[t]) { u.x = 0; u.y = 0; u.z = 0; u.w = 0; }
                    f16x8 b; __builtin_memcpy(&b, &u, 16);
                    if (r <= 2)
                        #pragma unroll
                        for (int ct = 0; ct < NCT; ++ct)
                            acc[0][t][ct] = __builtin_amdgcn_mfma_f32_16x16x32_f16(
                                afr[r * 2 + p][ct], b, acc[0][t][ct], 0, 0, 0);
                    if (r >= 1)
                        #pragma unroll
                        for (int ct = 0; ct < NCT; ++ct)
                            acc[1][t][ct] = __builtin_amdgcn_mfma_f32_16x16x32_f16(
                                afr[(r - 1) * 2 + p][ct], b, acc[1][t][ct], 0, 0, 0);
                }
        }
    }

    #pragma unroll
    for (int o = 0; o < 2; ++o) {
        char* ob = (char*)out
            + ((size_t)n * PLANE + (size_t)(y0 + o) * Wd + xw) * (COUT * 2);
        #pragma unroll
        for (int t = 0; t < 4; ++t)
            #pragma unroll
            for (int ct = 0; ct < NCT; ++ct) {
                float a0 = acc[o][t][ct][0], a1 = acc[o][t][ct][1];
                float a2 = acc[o][t][ct][2], a3 = acc[o][t][ct][3];
                if (RELU) {
                    a0 = fmaxf(a0, 0.f); a1 = fmaxf(a1, 0.f);
                    a2 = fmaxf(a2, 0.f); a3 = fmaxf(a3, 0.f);
                }
                ushort4 pk;
                pk.x = f2hu(a0); pk.y = f2hu(a1); pk.z = f2hu(a2); pk.w = f2hu(a3);
                *reinterpret_cast<ushort4*>(
                    ob + ((size_t)(t * 16 + lm) * COUT + ct * 16 + l4 * 4) * 2) = pk;
            }
    }

    if constexpr (POOL) {
        // fused 2x2 maxpool over the (y0, y0+1) row pair -> pooled row y0/2
        constexpr int HPL = (Wd >> 1) * (Wd >> 1);
        #pragma unroll
        for (int t = 0; t < 4; ++t) {
            const int col = xw + t * 16 + lm;
            #pragma unroll
            for (int ct = 0; ct < NCT; ++ct) {
                float m[4];
                #pragma unroll
                for (int rg = 0; rg < 4; ++rg) {
                    m[rg] = fmaxf(acc[0][t][ct][rg], acc[1][t][ct][rg]);
                    m[rg] = fmaxf(m[rg], __shfl_xor(m[rg], 1));
                }
                if ((lm & 1) == 0) {
                    ushort4 pk;
                    pk.x = f2hu(m[0]); pk.y = f2hu(m[1]);
                    pk.z = f2hu(m[2]); pk.w = f2hu(m[3]);
                    char* pb = (char*)pout
                        + (((size_t)n * HPL + (size_t)(y0 >> 1) * (Wd >> 1) + (col >> 1))
                           * COUT + ct * 16 + l4 * 4) * 2;
                    *reinterpret_cast<ushort4*>(pb) = pk;
                }
            }
        }
    }

    if constexpr (SPREP) {
        // fused S(p): feats part from f16-rounded acc (== stored feats),
        // cross-lane reduce over l4 groups, plus exact-f32 x part. NCT==1.
        float fpv[4];
        #pragma unroll
        for (int rg = 0; rg < 4; ++rg) fpv[rg] = fp[11 + l4 * 4 + rg];
        #pragma unroll
        for (int o = 0; o < 2; ++o) {
            #pragma unroll
            for (int t = 0; t < 4; ++t) {
                float s = 0.f;
                #pragma unroll
                for (int rg = 0; rg < 4; ++rg) {
                    const float v = (float)(f16)acc[o][t][0][rg];
                    s = fmaf(fpv[rg] * v, v, s);
                }
                s += __shfl_xor(s, 16);
                s += __shfl_xor(s, 32);
                if (l4 == 0) {
                    const int px = (y0 + o) * Wd + xw + t * 16 + lm;
                    const float* xp = xin + (size_t)n * 16 * PLANE + px;
                    #pragma unroll
                    for (int i = 0; i < 11; ++i) {
                        const float v = xp[(size_t)i * PLANE];
                        s = fmaf(fp[i] * v, v, s);
                    }
                    Sbuf[(size_t)n * PLANE + px] = s;
                }
            }
        }
    }
}

// ---------------------------------------------------------------------------
// ConvT 2x2 s2 + skip add via MFMA (f16, XCD-swizzled rows).
// ---------------------------------------------------------------------------
__global__ __launch_bounds__(256) void convTm_k(
    const f16* __restrict__ e, const f16* __restrict__ wpT,
    const float* __restrict__ bt, f16* __restrict__ du)
{
    __shared__ float lds[4][16 * 132];
    const int lane = threadIdx.x & 63;
    const int wv = threadIdx.x >> 6;
    const int l4 = lane >> 4, lm = lane & 15;
    const int n = blockIdx.y;
    const int row = xcdswz(blockIdx.x, 256);
    const int j0 = wv * 64;

    f16x8 afr[8];
    #pragma unroll
    for (int mt = 0; mt < 8; ++mt)
        __builtin_memcpy(&afr[mt], wpT + ((size_t)(mt * 64 + lane)) * 8, 16);

    float bco[8];
    #pragma unroll
    for (int mt = 0; mt < 8; ++mt) bco[mt] = bt[mt * 4 + l4];

    const char* ep = (const char*)e + ((size_t)n * 65536 + (size_t)row * 256 + j0) * 64;
    float* L = lds[wv];

    const int ra = lane >> 5;
    const int ru = lane & 31;
    const int rj = ru >> 1;
    const int rb = ru & 1;

    #pragma unroll 1
    for (int nt = 0; nt < 4; ++nt) {
        f16x8 bf;
        __builtin_memcpy(&bf, ep + (nt * 16 + lm) * 64 + l4 * 16, 16);

        #pragma unroll
        for (int mt = 0; mt < 8; ++mt) {
            f32x4 acc;
            acc[0] = bco[mt]; acc[1] = bco[mt]; acc[2] = bco[mt]; acc[3] = bco[mt];
            acc = __builtin_amdgcn_mfma_f32_16x16x32_f16(afr[mt], bf, acc, 0, 0, 0);
            float4 st; st.x = acc[0]; st.y = acc[1]; st.z = acc[2]; st.w = acc[3];
            *reinterpret_cast<float4*>(L + lm * 132 + mt * 16 + l4 * 4) = st;
        }
        __syncthreads();

        {
            const float* Ls = L + rj * 132 + ra * 2 + rb;
            char* dp = (char*)du
                + (((size_t)n * 262144
                    + (size_t)(2 * row + ra) * 512
                    + (size_t)(2 * (j0 + nt * 16 + rj) + rb)) * 32) * 2;
            float add[32];
            #pragma unroll
            for (int co = 0; co < 32; ++co) add[co] = Ls[co * 4];
            #pragma unroll
            for (int q = 0; q < 4; ++q) {
                uint4 u = *reinterpret_cast<const uint4*>(dp + q * 16);
                float dv[8]; unpk8(u, dv);
                unsigned short r[8];
                #pragma unroll
                for (int k = 0; k < 8; ++k) r[k] = f2hu(dv[k] + add[q * 8 + k]);
                __builtin_memcpy(dp + q * 16, r, 16);
            }
        }
        __syncthreads();
    }
}

// ---------------------------------------------------------------------------
// Bilateral, factored, y-PAIR, serial chains + f16 dot2 feats path,
// XCD-swizzled blocks (adjacent row-pairs share the +-4 tap-row window).
// ---------------------------------------------------------------------------
__global__ __launch_bounds__(256) void bil_k(
    const float* __restrict__ xin, const f16* __restrict__ feats,
    const float* __restrict__ Sbuf, const float* __restrict__ fp,
    float* __restrict__ out)
{
    constexpr int PLANE = 512 * 512;
    const int n = blockIdx.y;
    const int bx = xcdswz(blockIdx.x, 512);
    const int rp = bx >> 1;                               // row-pair 0..255
    const int xx = ((bx & 1) << 8) + threadIdx.x;         // 0..511
    const int y0 = ((rp >> 1) << 2) + (rp & 1);           // rows y0, y0+2

    const float sy = fp[27], sx = fp[28];

    const int p0 = y0 * 512 + xx;
    const float* xb = xin + (size_t)n * 16 * PLANE + p0;
    const char* fb = (const char*)feats + ((size_t)n * PLANE + p0) * 32;
    const float* Sb = Sbuf + (size_t)n * PLANE + p0;

    float g0[11], g1[11];
    #pragma unroll
    for (int i = 0; i < 11; ++i) {
        g0[i] = fp[i] * xb[(size_t)i * PLANE];
        g1[i] = fp[i] * xb[(size_t)i * PLANE + 1024];
    }
    unsigned int g0h[8], g1h[8];
    {
        uint4 cu0 = *reinterpret_cast<const uint4*>(fb);
        uint4 cu1 = *reinterpret_cast<const uint4*>(fb + 16);
        const unsigned int* cq = (const unsigned int*)&cu0;
        const unsigned int* cq2 = (const unsigned int*)&cu1;
        #pragma unroll
        for (int j = 0; j < 8; ++j) {
            const unsigned int q = (j < 4) ? cq[j] : cq2[j - 4];
            g0h[j] = packh2(fp[11 + 2 * j] * hu2f(q & 0xffffu),
                            fp[12 + 2 * j] * hu2f(q >> 16));
        }
        cu0 = *reinterpret_cast<const uint4*>(fb + 32768);
        cu1 = *reinterpret_cast<const uint4*>(fb + 32768 + 16);
        #pragma unroll
        for (int j = 0; j < 8; ++j) {
            const unsigned int q = (j < 4) ? ((const unsigned int*)&cu0)[j]
                                           : ((const unsigned int*)&cu1)[j - 4];
            g1h[j] = packh2(fp[11 + 2 * j] * hu2f(q & 0xffffu),
                            fp[12 + 2 * j] * hu2f(q >> 16));
        }
    }
    const float Sp0 = Sb[0];
    const float Sp1 = Sb[1024];

    float num0[11], num1[11];
    #pragma unroll
    for (int i = 0; i < 11; ++i) { num0[i] = 0.f; num1[i] = 0.f; }
    float den0 = 0.f, den1 = 0.f;

    #pragma unroll
    for (int o = -4; o <= 6; o += 2) {
        const int r = y0 + o;
        if ((unsigned)r > 511u) continue;                 // uniform per block
        const float b0 = fmaf(sy, (float)(o * o), Sp0);
        const float b1 = fmaf(sy, (float)((o - 2) * (o - 2)), Sp1);
        const float* xr = xb + o * 512;
        const char* fr = fb + (ptrdiff_t)o * 512 * 32;
        const float* Sr = Sb + o * 512;
        #pragma unroll
        for (int dx = -2; dx <= 2; ++dx) {
            const int xv = xx + 2 * dx;
            if ((unsigned)xv > 511u) continue;            // edge lanes only
            const int off = dx * 2;

            float sv[11];
            #pragma unroll
            for (int i = 0; i < 11; ++i) sv[i] = xr[(size_t)i * PLANE + off];
            const uint4 u0 = *reinterpret_cast<const uint4*>(fr + off * 32);
            const uint4 u1 = *reinterpret_cast<const uint4*>(fr + off * 32 + 16);
            const unsigned int* fq = (const unsigned int*)&u0;
            const unsigned int* fq2 = (const unsigned int*)&u1;
            const float Sq = Sr[off] + sx * (float)(4 * dx * dx);

            if (o <= 4) {                                 // p0 tap
                float cr = g0[0] * sv[0];
                #pragma unroll
                for (int i = 1; i < 11; ++i) cr = fmaf(g0[i], sv[i], cr);
                #pragma unroll
                for (int j = 0; j < 8; ++j)
                    cr = dotacc(g0h[j], (j < 4) ? fq[j] : fq2[j - 4], cr);
                const float w = __expf(fmaf(-2.0f, cr, Sq + b0));
                #pragma unroll
                for (int i = 0; i < 11; ++i) num0[i] = fmaf(w, sv[i], num0[i]);
                den0 += w;
            }
            if (o >= -2) {                                // p1 tap
                float cr = g1[0] * sv[0];
                #pragma unroll
                for (int i = 1; i < 11; ++i) cr = fmaf(g1[i], sv[i], cr);
                #pragma unroll
                for (int j = 0; j < 8; ++j)
                    cr = dotacc(g1h[j], (j < 4) ? fq[j] : fq2[j - 4], cr);
                const float w = __expf(fmaf(-2.0f, cr, Sq + b1));
                #pragma unroll
                for (int i = 0; i < 11; ++i) num1[i] = fmaf(w, sv[i], num1[i]);
                den1 += w;
            }
        }
    }

    const float i0 = 1.f / den0, i1 = 1.f / den1;
    float* ob = out + (size_t)n * 11 * PLANE + p0;
    #pragma unroll
    for (int i = 0; i < 11; ++i) {
        ob[(size_t)i * PLANE] = num0[i] * i0;
        ob[(size_t)i * PLANE + 1024] = num1[i] * i1;
    }
}

// ---------------------------------------------------------------------------
extern "C" void kernel_launch(void* const* d_in, const int* in_sizes, int n_in,
                              void* d_out, int out_size, void* d_ws, size_t ws_size,
                              hipStream_t stream)
{
    const float* x = (const float*)d_in[0];
    const float* Wv[9];
    const float* Bv[9];
    if (in_sizes[2] == 16) {
        for (int i = 0; i < 9; ++i) {
            Wv[i] = (const float*)d_in[1 + 2 * i];
            Bv[i] = (const float*)d_in[2 + 2 * i];
        }
    } else {
        for (int i = 0; i < 9; ++i) {
            Wv[i] = (const float*)d_in[1 + i];
            Bv[i] = (const float*)d_in[10 + i];
        }
    }
    const float* wt = (const float*)d_in[19];
    const float* bt = (const float*)d_in[20];
    const float* fp = (const float*)d_in[21];
    float* out = (float*)d_out;

    constexpr size_t MiB = 1ull << 20;
    char* ws = (char*)d_ws;

    f16* wp  = (f16*)(ws + 4096);
    f16* wpT = (f16*)(ws + 256 * 1024);
    f16 *xh, *du, *bufA, *bufB;
    if (ws_size >= 165 * MiB) {
        xh   = (f16*)(ws + 1 * MiB);
        du   = (f16*)(ws + 34 * MiB);
        bufA = (f16*)(ws + 99 * MiB);
        bufB = (f16*)(ws + 132 * MiB);
    } else if (ws_size >= 132 * MiB) {
        xh   = (f16*)(ws + 1 * MiB);
        du   = (f16*)(ws + 34 * MiB);
        bufA = (f16*)(ws + 99 * MiB);
        bufB = xh;
    } else {
        xh   = (f16*)((char*)d_out + 256);
        du   = (f16*)(ws + 1 * MiB);
        bufA = (f16*)(ws + 66 * MiB);
        bufB = xh;
    }
    float* Sbuf = (float*)du;   // du dead after conv6; reused for S (4 MiB)

    WSrc srcs;
    for (int i = 0; i < 9; ++i) srcs.w[i] = Wv[i];
    srcs.w[9] = wt;

    prep_k<<<10, 256, 0, stream>>>(srcs, wp, wpT);
    xtonhwc_k<<<4096, 256, 0, stream>>>(x, xh);

    const dim3 blk(256);
    const dim3 g512(512, 4);    // 512^2: 256 row-pairs x 2 col halves
    const dim3 g256(128, 4);    // 256^2: 128 row-pairs x 1
    const dim3 gT(256, 4);

    convm2_k<16, 16, true,  9, false, false><<<g512, blk, 0, stream>>>(
        xh,   wp + 0,     Bv[0], bufA, nullptr, nullptr, nullptr, nullptr);
    convm2_k<16, 16, true,  9, false, false><<<g512, blk, 0, stream>>>(
        bufA, wp + 3072,  Bv[1], bufB, nullptr, nullptr, nullptr, nullptr);
    // conv2 + fused 2x2 maxpool (pooled e -> bufA)
    convm2_k<16, 32, false, 9, true,  false><<<g512, blk, 0, stream>>>(
        bufB, wp + 6144,  Bv[2], du,   bufA,    nullptr, nullptr, nullptr);

    convm2_k<32, 32, true,  8, false, false><<<g256, blk, 0, stream>>>(
        bufA, wp + 12288, Bv[3], bufB, nullptr, nullptr, nullptr, nullptr);
    convm2_k<32, 32, true,  8, false, false><<<g256, blk, 0, stream>>>(
        bufB, wp + 21504, Bv[4], bufA, nullptr, nullptr, nullptr, nullptr);
    convm2_k<32, 32, true,  8, false, false><<<g256, blk, 0, stream>>>(
        bufA, wp + 30720, Bv[5], bufB, nullptr, nullptr, nullptr, nullptr);

    convTm_k<<<gT, blk, 0, stream>>>(bufB, wpT, bt, du);

    convm2_k<32, 16, true,  9, false, false><<<g512, blk, 0, stream>>>(
        du,   wp + 39936, Bv[6], bufA, nullptr, nullptr, nullptr, nullptr);
    convm2_k<16, 16, true,  9, false, false><<<g512, blk, 0, stream>>>(
        bufA, wp + 44544, Bv[7], bufB, nullptr, nullptr, nullptr, nullptr);
    // conv8 + fused S precompute (feats -> bufA, S -> Sbuf in dead du region)
    convm2_k<16, 16, false, 9, false, true ><<<g512, blk, 0, stream>>>(
        bufB, wp + 47616, Bv[8], bufA, nullptr, x, fp, Sbuf);

    bil_k<<<dim3(512, 4), blk, 0, stream>>>(x, bufA, Sbuf, fp, out);

    (void)n_in; (void)out_size;
}